// Round 9
// baseline (977.119 us; speedup 1.0000x reference)
//
#include <hip/hip_runtime.h>

#define T_DIM 1024
#define B_DIM 512
#define OBS_DIM 64
#define H_DIM 128
#define G3 384
#define A_DIM 16
#define CT 256
#define NCHUNK 4

typedef __bf16 bf16;
typedef __attribute__((ext_vector_type(4))) __bf16 bf16x4;
typedef __attribute__((ext_vector_type(8))) __bf16 bf16x8;
typedef __attribute__((ext_vector_type(4))) float f32x4;

#define MFMA(a, b, c) __builtin_amdgcn_mfma_f32_16x16x32_bf16((a), (b), (c), 0, 0, 0)

__device__ __forceinline__ float sigm(float x) { return 1.0f / (1.0f + __expf(-x)); }
__device__ __forceinline__ float tanh_f(float x) { return 1.0f - 2.0f / (__expf(2.0f * x) + 1.0f); }
// pick element q (runtime 0..3) from f32x4 with static indices (3 cndmask)
__device__ __forceinline__ float sel4(f32x4 v, int qa, int qb) {
  float lo = qa ? v[1] : v[0];
  float hi = qa ? v[3] : v[2];
  return qb ? hi : lo;
}

// ---------------- prep: bf16 transposed weights + h_state init ----------------
__global__ __launch_bounds__(256) void prep_k(
    const float* __restrict__ hidden, const int* __restrict__ dones,
    const float* __restrict__ W_emb, const float* __restrict__ Wi,
    const float* __restrict__ Wh, const float* __restrict__ Wa1,
    const float* __restrict__ Wa2, const float* __restrict__ Wc1,
    const float* __restrict__ Wc2,
    bf16* __restrict__ wembT, bf16* __restrict__ wiT, bf16* __restrict__ whT,
    bf16* __restrict__ wa1T, bf16* __restrict__ wa2T, bf16* __restrict__ wc1T,
    bf16* __restrict__ wc2T, float* __restrict__ h_state) {
  int i = blockIdx.x * 256 + threadIdx.x;
  if (i < 8192) { int n = i / OBS_DIM, k = i % OBS_DIM; wembT[i] = (bf16)W_emb[k * H_DIM + n]; return; }
  i -= 8192;
  if (i < 49152) { int g = i / H_DIM, k = i % H_DIM; wiT[i] = (bf16)Wi[k * G3 + g]; return; }
  i -= 49152;
  if (i < 49152) { int g = i / H_DIM, k = i % H_DIM; whT[i] = (bf16)Wh[k * G3 + g]; return; }
  i -= 49152;
  if (i < 16384) { int n = i / H_DIM, k = i % H_DIM; wa1T[i] = (bf16)Wa1[k * H_DIM + n]; return; }
  i -= 16384;
  if (i < 2048) { int a = i / H_DIM, k = i % H_DIM; wa2T[i] = (bf16)Wa2[k * A_DIM + a]; return; }
  i -= 2048;
  if (i < 16384) { int n = i / H_DIM, k = i % H_DIM; wc1T[i] = (bf16)Wc1[k * H_DIM + n]; return; }
  i -= 16384;
  if (i < 2048) { int r = i / H_DIM, k = i % H_DIM; wc2T[i] = (r == 0) ? (bf16)Wc2[k] : (bf16)0.0f; return; }
  i -= 2048;
  if (i < 65536) { int b = i / H_DIM; h_state[i] = dones[b] ? 0.0f : hidden[i]; return; }
}

// ================= role bodies (share one 32-KiB LDS block) ==================

// ---- phase1 body: weight-stationary, ntiles x 16 rows -----------------------
__device__ __forceinline__ void phase1_body(
    char* smem, int tile_base, int ntiles, const float* __restrict__ obs,
    const float* __restrict__ b_emb, const float* __restrict__ bi,
    const bf16* __restrict__ wembT, const bf16* __restrict__ wiT,
    bf16* __restrict__ xi, int row_base) {
  bf16 (*obs_lds)[72]  = (bf16(*)[72])smem;            // 2304 B
  bf16 (*emb_lds)[136] = (bf16(*)[136])(smem + 2304);  // 4352 B
  bf16 (*strip)[392]   = (bf16(*)[392])(smem + 6656);  // 12544 B
  int tid = threadIdx.x, wave = tid >> 6, lane = tid & 63;
  int nl = lane & 15, q = lane >> 4;

  bf16x8 we[2][2], wi_f[6][4];
  float bev[2], biv[6];
#pragma unroll
  for (int e = 0; e < 2; ++e) {
    int nt = wave * 2 + e;
#pragma unroll
    for (int kb = 0; kb < 2; ++kb)
      we[e][kb] = *(const bf16x8*)(wembT + (nt * 16 + nl) * OBS_DIM + kb * 32 + q * 8);
    bev[e] = b_emb[nt * 16 + nl];
  }
#pragma unroll
  for (int j = 0; j < 6; ++j) {
    int nt = wave * 6 + j;
#pragma unroll
    for (int kb = 0; kb < 4; ++kb)
      wi_f[j][kb] = *(const bf16x8*)(wiT + (nt * 16 + nl) * H_DIM + kb * 32 + q * 8);
    biv[j] = bi[nt * 16 + nl];
  }

  int srow = tid >> 4, scol = (tid & 15) * 4;
  for (int rt = 0; rt < ntiles; ++rt) {
    int r0 = (tile_base + rt) * 16;  // chunk-local row base
    {   // stage obs tile (f32 -> bf16), 256 thr x 1 float4
      const float* src = obs + ((long)row_base + r0 + srow) * OBS_DIM + scol;
      float4 vv = *(const float4*)src;
      bf16x4 b; b[0] = (bf16)vv.x; b[1] = (bf16)vv.y; b[2] = (bf16)vv.z; b[3] = (bf16)vv.w;
      *(bf16x4*)&obs_lds[srow][scol] = b;
    }
    __syncthreads();
    bf16x8 ao[2];
#pragma unroll
    for (int kb = 0; kb < 2; ++kb) ao[kb] = *(const bf16x8*)&obs_lds[nl][kb * 32 + q * 8];
#pragma unroll
    for (int e = 0; e < 2; ++e) {
      f32x4 c = {0.f, 0.f, 0.f, 0.f};
      c = MFMA(ao[0], we[e][0], c);
      c = MFMA(ao[1], we[e][1], c);
#pragma unroll
      for (int r = 0; r < 4; ++r) {
        float v = c[r] + bev[e];
        emb_lds[q * 4 + r][(wave * 2 + e) * 16 + nl] = (bf16)(v > 0.f ? v : 0.f);
      }
    }
    __syncthreads();
    bf16x8 ae[4];
#pragma unroll
    for (int kb = 0; kb < 4; ++kb) ae[kb] = *(const bf16x8*)&emb_lds[nl][kb * 32 + q * 8];
#pragma unroll
    for (int j = 0; j < 6; ++j) {
      int nt = wave * 6 + j;
      f32x4 c = {0.f, 0.f, 0.f, 0.f};
#pragma unroll
      for (int kb = 0; kb < 4; ++kb) c = MFMA(ae[kb], wi_f[j][kb], c);
      int gate = nt >> 3, dloc = (nt & 7) * 16 + nl;
      int pos = (gate < 2) ? (2 * dloc + gate) : (256 + dloc);
#pragma unroll
      for (int r = 0; r < 4; ++r) strip[q * 4 + r][pos] = (bf16)(c[r] + biv[j]);
    }
    __syncthreads();
    bf16* dst = xi + (long)r0 * G3;
#pragma unroll
    for (int it = 0; it < 3; ++it) {
      int e0 = (it * 256 + tid) * 8;
      int row = e0 / G3, col = e0 % G3;
      *(int4*)(dst + e0) = *(const int4*)&strip[row][col];
    }
    __syncthreads();
  }
}

// ---- scan body: GRU over CT steps, 4 chains per block (dedicated CU) --------
// hb[2 dbuf][4 chains][136]: A-row nl reads hb[nl&3] -> replication happens
// through ADDRESSING (row 4q+r = chain r), writes are 2 ds_write_b16/thread.
// Each thread owns chain q at dims {d0, d0+64}. acc initialized via the first
// MFMA with a persistent zero vector (no per-step accvgpr movs).
__device__ __forceinline__ void scan_body(
    char* smem, int bid, const bf16* __restrict__ xi,
    const int* __restrict__ dones, const float* __restrict__ bh_n,
    const bf16* __restrict__ whT, float* __restrict__ h_state,
    bf16* __restrict__ y, float* __restrict__ hidden_out, int chunk) {
  bf16 (*hb)[4][136]       = (bf16(*)[4][136])smem;               // 2176 B
  bf16 (*xibuf)[4][4][400] = (bf16(*)[4][4][400])(smem + 2176);   // 25600 B
  int  (*dn)[4]            = (int(*)[4])(smem + 27776);           // 4112 B

  __builtin_amdgcn_s_setprio(1);

  int tid = threadIdx.x;
  int wave = tid >> 6, lane = tid & 63;
  int nl = lane & 15, q = lane >> 4;
  int b0 = bid * 4;
  int d0 = wave * 16 + nl, d1 = d0 + 64;
  int hrow = nl & 3;
  int qa = q & 1, qb = q >> 1;

  for (int i = tid; i <= CT; i += 256) {
    int t = chunk * CT + i;
    if (t < T_DIM) *(int4*)&dn[i][0] = *(const int4*)&dones[t * B_DIM + b0];
    else { dn[i][0] = 0; dn[i][1] = 0; dn[i][2] = 0; dn[i][3] = 0; }
  }
  // staging slots: 768 int4 per 4-step group (4 steps x 4 chains x 384 bf16)
  int c0 = tid, c1 = 256 + tid, c2 = 512 + tid;
  int t0 = c0 / 192, r0_ = c0 % 192, sc0 = r0_ / 48, o0 = (r0_ % 48) * 8;
  int t1 = c1 / 192, r1_ = c1 % 192, sc1 = r1_ / 48, o1 = (r1_ % 48) * 8;
  int t2 = c2 / 192, r2_ = c2 % 192, sc2 = r2_ / 48, o2 = (r2_ % 48) * 8;
  const long PSTR = (long)4 * B_DIM * G3;
  const bf16* pfs0 = xi + ((long)(4 + t0) * B_DIM + b0 + sc0) * G3 + o0;
  const bf16* pfs1 = xi + ((long)(4 + t1) * B_DIM + b0 + sc1) * G3 + o1;
  const bf16* pfs2 = xi + ((long)(4 + t2) * B_DIM + b0 + sc2) * G3 + o2;
  *(int4*)&xibuf[0][t0][sc0][o0] = *(const int4*)(xi + ((long)t0 * B_DIM + b0 + sc0) * G3 + o0);
  *(int4*)&xibuf[0][t1][sc1][o1] = *(const int4*)(xi + ((long)t1 * B_DIM + b0 + sc1) * G3 + o1);
  *(int4*)&xibuf[0][t2][sc2][o2] = *(const int4*)(xi + ((long)t2 * B_DIM + b0 + sc2) * G3 + o2);

  float hprev0 = h_state[(b0 + q) * H_DIM + d0];
  float hprev1 = h_state[(b0 + q) * H_DIM + d1];
  hb[0][q][d0] = (bf16)hprev0;
  hb[0][q][d1] = (bf16)hprev1;

  bf16x8 wf[6][4];
#pragma unroll
  for (int g = 0; g < 3; ++g)
#pragma unroll
    for (int hI = 0; hI < 2; ++hI)
#pragma unroll
      for (int kb = 0; kb < 4; ++kb)
        wf[g * 2 + hI][kb] =
            *(const bf16x8*)(whT + ((g * 8 + wave + 4 * hI) * 16 + nl) * H_DIM + kb * 32 + q * 8);
  float bhn0 = bh_n[d0], bhn1 = bh_n[d1];
  bf16* yp0 = y + (long)(b0 + q) * H_DIM + d0;
  bf16* yp1 = y + (long)(b0 + q) * H_DIM + d1;
  const f32x4 zero = {0.f, 0.f, 0.f, 0.f};
  __syncthreads();

  int4 pfr0, pfr1, pfr2;

#define BAR()                                                                  \
  do {                                                                         \
    asm volatile("s_waitcnt lgkmcnt(0)" ::: "memory");                         \
    __builtin_amdgcn_sched_barrier(0);                                         \
    __builtin_amdgcn_s_barrier();                                              \
    __builtin_amdgcn_sched_barrier(0);                                         \
  } while (0)

#define MSTEP(HA, KB)                                                          \
  do {                                                                         \
    c0_ = MFMA(HA, wf[0][KB], c0_); c1_ = MFMA(HA, wf[1][KB], c1_);            \
    c2_ = MFMA(HA, wf[2][KB], c2_); c3_ = MFMA(HA, wf[3][KB], c3_);            \
    c4_ = MFMA(HA, wf[4][KB], c4_); c5_ = MFMA(HA, wf[5][KB], c5_);            \
  } while (0)

#define GSTEP(CUR, TS, TB, PF)                                                 \
  do {                                                                         \
    const int p_ = (TS) & 1;                                                   \
    bf16x8 ha0 = *(const bf16x8*)&hb[p_][hrow][0 * 32 + q * 8];                \
    bf16x8 ha1 = *(const bf16x8*)&hb[p_][hrow][1 * 32 + q * 8];                \
    bf16x8 ha2 = *(const bf16x8*)&hb[p_][hrow][2 * 32 + q * 8];                \
    bf16x8 ha3 = *(const bf16x8*)&hb[p_][hrow][3 * 32 + q * 8];                \
    const bf16* xrow_ = &xibuf[CUR][TS][q][0];                                 \
    unsigned urz0_ = *(const unsigned*)(xrow_ + 2 * d0);                       \
    unsigned urz1_ = *(const unsigned*)(xrow_ + 2 * d1);                       \
    float xn0_ = (float)xrow_[256 + d0];                                       \
    float xn1_ = (float)xrow_[256 + d1];                                       \
    int dnv_ = dn[(TB) + (TS) + 1][q];                                         \
    if ((TS) == 0 && (PF)) {                                                   \
      pfr0 = *(const int4*)pfs0; pfs0 += PSTR;                                 \
      pfr1 = *(const int4*)pfs1; pfs1 += PSTR;                                 \
      pfr2 = *(const int4*)pfs2; pfs2 += PSTR;                                 \
    }                                                                          \
    f32x4 c0_ = MFMA(ha0, wf[0][0], zero), c1_ = MFMA(ha0, wf[1][0], zero);    \
    f32x4 c2_ = MFMA(ha0, wf[2][0], zero), c3_ = MFMA(ha0, wf[3][0], zero);    \
    f32x4 c4_ = MFMA(ha0, wf[4][0], zero), c5_ = MFMA(ha0, wf[5][0], zero);    \
    MSTEP(ha1, 1); MSTEP(ha2, 2); MSTEP(ha3, 3);                               \
    if ((TS) == 3 && (PF)) {                                                   \
      *(int4*)&xibuf[(CUR) ^ 1][t0][sc0][o0] = pfr0;                           \
      *(int4*)&xibuf[(CUR) ^ 1][t1][sc1][o1] = pfr1;                           \
      *(int4*)&xibuf[(CUR) ^ 1][t2][sc2][o2] = pfr2;                           \
    }                                                                          \
    float hr0_ = sel4(c0_, qa, qb), hr1_ = sel4(c1_, qa, qb);                  \
    float hz0_ = sel4(c2_, qa, qb), hz1_ = sel4(c3_, qa, qb);                  \
    float hn0_ = sel4(c4_, qa, qb), hn1_ = sel4(c5_, qa, qb);                  \
    union { unsigned u; float f; } a0u_, b0u_, a1u_, b1u_;                     \
    a0u_.u = urz0_ << 16; b0u_.u = urz0_ & 0xffff0000u;                        \
    a1u_.u = urz1_ << 16; b1u_.u = urz1_ & 0xffff0000u;                        \
    float r0g_ = sigm(a0u_.f + hr0_), r1g_ = sigm(a1u_.f + hr1_);              \
    float z0g_ = sigm(b0u_.f + hz0_), z1g_ = sigm(b1u_.f + hz1_);              \
    float n0g_ = tanh_f(xn0_ + r0g_ * (hn0_ + bhn0));                          \
    float n1g_ = tanh_f(xn1_ + r1g_ * (hn1_ + bhn1));                          \
    float hnew0_ = (1.0f - z0g_) * n0g_ + z0g_ * hprev0;                       \
    float hnew1_ = (1.0f - z1g_) * n1g_ + z1g_ * hprev1;                       \
    float heff0_ = dnv_ ? 0.0f : hnew0_;                                       \
    float heff1_ = dnv_ ? 0.0f : hnew1_;                                       \
    *yp0 = (bf16)hnew0_; yp0 += B_DIM * H_DIM;                                 \
    *yp1 = (bf16)hnew1_; yp1 += B_DIM * H_DIM;                                 \
    hb[p_ ^ 1][q][d0] = (bf16)heff0_;                                          \
    hb[p_ ^ 1][q][d1] = (bf16)heff1_;                                          \
    hprev0 = heff0_; hprev1 = heff1_;                                          \
    BAR();                                                                     \
  } while (0)

  for (int tb = 0; tb < CT; tb += 8) {
    GSTEP(0, 0, tb, 1); GSTEP(0, 1, tb, 1); GSTEP(0, 2, tb, 1); GSTEP(0, 3, tb, 1);
    const int pfB = (tb + 8 < CT) ? 1 : 0;
    GSTEP(1, 0, tb + 4, pfB); GSTEP(1, 1, tb + 4, pfB);
    GSTEP(1, 2, tb + 4, pfB); GSTEP(1, 3, tb + 4, pfB);
  }
#undef GSTEP
#undef MSTEP
#undef BAR
  __builtin_amdgcn_s_setprio(0);

  // heff(last) == hnew(last) on the final chunk: dn[CT] there is 0 (t >= T_DIM)
  h_state[(b0 + q) * H_DIM + d0] = hprev0;
  h_state[(b0 + q) * H_DIM + d1] = hprev1;
  if (chunk == NCHUNK - 1) {
    hidden_out[(b0 + q) * H_DIM + d0] = hprev0;
    hidden_out[(b0 + q) * H_DIM + d1] = hprev1;
  }
}

// ---- heads body: weight-stationary, ntiles x 16 rows ------------------------
__device__ __forceinline__ void heads_body(
    char* smem, int tile_base, int ntiles, const bf16* __restrict__ y,
    const float* __restrict__ ba1, const float* __restrict__ ba2,
    const float* __restrict__ bc1, const float* __restrict__ bc2,
    const bf16* __restrict__ wa1T, const bf16* __restrict__ wa2T,
    const bf16* __restrict__ wc1T, const bf16* __restrict__ wc2T,
    float* __restrict__ logits, float* __restrict__ v, int t_base) {
  bf16  (*y_lds)[136] = (bf16(*)[136])smem;              // 4352 B
  bf16  (*a1s)[136]   = (bf16(*)[136])(smem + 4352);     // 4352 B
  bf16  (*c1s)[136]   = (bf16(*)[136])(smem + 8704);     // 4352 B
  float (*s_o)[16]    = (float(*)[16])(smem + 13056);    // 1024 B
  float (*s_v)        = (float*)(smem + 14080);          // 64 B
  int tid = threadIdx.x, wave = tid >> 6, lane = tid & 63;
  int nl = lane & 15, q = lane >> 4;

  bf16x8 wa1f[2][4], wc1f[2][4], wa2f[4], wc2f[4];
  float ba1v[2], bc1v[2];
#pragma unroll
  for (int e = 0; e < 2; ++e) {
    int nt = wave * 2 + e;
#pragma unroll
    for (int kb = 0; kb < 4; ++kb) {
      wa1f[e][kb] = *(const bf16x8*)(wa1T + (nt * 16 + nl) * H_DIM + kb * 32 + q * 8);
      wc1f[e][kb] = *(const bf16x8*)(wc1T + (nt * 16 + nl) * H_DIM + kb * 32 + q * 8);
    }
    ba1v[e] = ba1[nt * 16 + nl];
    bc1v[e] = bc1[nt * 16 + nl];
  }
#pragma unroll
  for (int kb = 0; kb < 4; ++kb) {
    wa2f[kb] = *(const bf16x8*)(wa2T + nl * H_DIM + kb * 32 + q * 8);
    wc2f[kb] = *(const bf16x8*)(wc2T + nl * H_DIM + kb * 32 + q * 8);
  }
  float ba2v = ba2[nl], bc2v = bc2[0];

  int srow = tid >> 4, scol = (tid & 15) * 8;
  for (int rt = 0; rt < ntiles; ++rt) {
    int r0 = (tile_base + rt) * 16;        // chunk-local row base
    long gr0 = (long)t_base * B_DIM + r0;  // global row base
    *(int4*)&y_lds[srow][scol] = *(const int4*)(y + (long)(r0 + srow) * H_DIM + scol);
    __syncthreads();
    bf16x8 ya[4];
#pragma unroll
    for (int kb = 0; kb < 4; ++kb) ya[kb] = *(const bf16x8*)&y_lds[nl][kb * 32 + q * 8];
#pragma unroll
    for (int e = 0; e < 2; ++e) {
      f32x4 ca = {0.f, 0.f, 0.f, 0.f}, cc = {0.f, 0.f, 0.f, 0.f};
#pragma unroll
      for (int kb = 0; kb < 4; ++kb) {
        ca = MFMA(ya[kb], wa1f[e][kb], ca);
        cc = MFMA(ya[kb], wc1f[e][kb], cc);
      }
      int colb = (wave * 2 + e) * 16 + nl;
#pragma unroll
      for (int r = 0; r < 4; ++r) {
        float va = ca[r] + ba1v[e];
        float vc = cc[r] + bc1v[e];
        a1s[q * 4 + r][colb] = (bf16)(va > 0.f ? va : 0.f);
        c1s[q * 4 + r][colb] = (bf16)(vc > 0.f ? vc : 0.f);
      }
    }
    __syncthreads();
    if (wave == 0) {
      bf16x8 a1f[4];
#pragma unroll
      for (int kb = 0; kb < 4; ++kb) a1f[kb] = *(const bf16x8*)&a1s[nl][kb * 32 + q * 8];
      f32x4 c = {0.f, 0.f, 0.f, 0.f};
#pragma unroll
      for (int kb = 0; kb < 4; ++kb) c = MFMA(a1f[kb], wa2f[kb], c);
#pragma unroll
      for (int r = 0; r < 4; ++r) s_o[q * 4 + r][nl] = c[r] + ba2v;
    } else if (wave == 1) {
      bf16x8 c1f[4];
#pragma unroll
      for (int kb = 0; kb < 4; ++kb) c1f[kb] = *(const bf16x8*)&c1s[nl][kb * 32 + q * 8];
      f32x4 c = {0.f, 0.f, 0.f, 0.f};
#pragma unroll
      for (int kb = 0; kb < 4; ++kb) c = MFMA(c1f[kb], wc2f[kb], c);
      if (nl == 0) {
#pragma unroll
        for (int r = 0; r < 4; ++r) s_v[q * 4 + r] = c[r] + bc2v;
      }
    }
    __syncthreads();
    if (tid < 64) {
      *(int4*)(logits + gr0 * A_DIM + tid * 4) = *(const int4*)&s_o[tid >> 2][(tid & 3) * 4];
    } else if (tid < 80) {
      v[gr0 + (tid - 64)] = s_v[tid - 64];
    }
    __syncthreads();
  }
}

// ---- fused pipeline: scan(cs) on CUs 0..127 ∥ workers on CUs 128..255 --------
// grid 256 = 1 block/CU: 128 scan blocks (4 chains each) run UNCONTENDED;
// 128 worker blocks do phase1(cs+1)+heads(cs-1) on their own CUs.
__global__ __launch_bounds__(256, 1) void fused_k(
    const float* __restrict__ obs, const float* __restrict__ b_emb,
    const float* __restrict__ bi, const bf16* __restrict__ wembT,
    const bf16* __restrict__ wiT, bf16* __restrict__ xi0, bf16* __restrict__ xi1,
    const int* __restrict__ dones, const float* __restrict__ bh_n,
    const bf16* __restrict__ whT, float* __restrict__ h_state,
    bf16* __restrict__ y0, bf16* __restrict__ y1, float* __restrict__ hidden_out,
    const float* __restrict__ ba1, const float* __restrict__ ba2,
    const float* __restrict__ bc1, const float* __restrict__ bc2,
    const bf16* __restrict__ wa1T, const bf16* __restrict__ wa2T,
    const bf16* __restrict__ wc1T, const bf16* __restrict__ wc2T,
    float* __restrict__ logits, float* __restrict__ v, int cs) {
  __shared__ __align__(16) char smem[32768];
  int bid = blockIdx.x;
  if (cs == -1) {  // wide edge: phase1(0) over all 256 blocks
    phase1_body(smem, bid * 32, 32, obs, b_emb, bi, wembT, wiT, xi0, 0);
    return;
  }
  if (cs == NCHUNK) {  // wide edge: heads(NCHUNK-1) over all 256 blocks
    heads_body(smem, bid * 32, 32, ((NCHUNK - 1) & 1) ? y1 : y0, ba1, ba2, bc1,
               bc2, wa1T, wa2T, wc1T, wc2T, logits, v, (NCHUNK - 1) * CT);
    return;
  }
  if (bid < 128) {
    scan_body(smem, bid, (cs & 1) ? xi1 : xi0, dones, bh_n, whT, h_state,
              (cs & 1) ? y1 : y0, hidden_out, cs);
    return;
  }
  {  // worker on its own CU
    int wb = bid - 128;
    int cp = cs + 1;
    if (cp < NCHUNK)
      phase1_body(smem, wb * 64, 64, obs, b_emb, bi, wembT, wiT,
                  (cp & 1) ? xi1 : xi0, cp * CT * B_DIM);
    int c2 = cs - 1;
    if (c2 >= 0)
      heads_body(smem, wb * 64, 64, (c2 & 1) ? y1 : y0, ba1, ba2, bc1, bc2,
                 wa1T, wa2T, wc1T, wc2T, logits, v, c2 * CT);
  }
}

// ---------------- launch ------------------------------------------------------
extern "C" void kernel_launch(void* const* d_in, const int* in_sizes, int n_in,
                              void* d_out, int out_size, void* d_ws, size_t ws_size,
                              hipStream_t stream) {
  const float* hidden = (const float*)d_in[0];
  const float* obs    = (const float*)d_in[1];
  const int*   dones  = (const int*)d_in[2];
  const float* W_emb  = (const float*)d_in[3];
  const float* b_emb  = (const float*)d_in[4];
  const float* Wi     = (const float*)d_in[5];
  const float* bi     = (const float*)d_in[6];
  const float* Wh     = (const float*)d_in[7];
  const float* bh_n   = (const float*)d_in[8];
  const float* Wa1    = (const float*)d_in[9];
  const float* ba1    = (const float*)d_in[10];
  const float* Wa2    = (const float*)d_in[11];
  const float* ba2    = (const float*)d_in[12];
  const float* Wc1    = (const float*)d_in[13];
  const float* bc1    = (const float*)d_in[14];
  const float* Wc2    = (const float*)d_in[15];
  const float* bc2    = (const float*)d_in[16];

  float* out_hidden = (float*)d_out;
  float* out_logits = out_hidden + B_DIM * H_DIM;
  float* out_v      = out_logits + (long)T_DIM * B_DIM * A_DIM;

  char* ws = (char*)d_ws;
  bf16*  wembT   = (bf16*)(ws + 0);
  bf16*  wiT     = (bf16*)(ws + 16384);
  bf16*  whT     = (bf16*)(ws + 114688);
  bf16*  wa1T    = (bf16*)(ws + 212992);
  bf16*  wa2T    = (bf16*)(ws + 245760);
  bf16*  wc1T    = (bf16*)(ws + 249856);
  bf16*  wc2T    = (bf16*)(ws + 282624);
  float* h_state = (float*)(ws + 286720);
  bf16*  xi0     = (bf16*)(ws + 548864);       // 100.66 MB per chunk buffer
  bf16*  xi1     = (bf16*)(ws + 101212160);
  bf16*  y0      = (bf16*)(ws + 201875456);    // 33.55 MB per chunk buffer
  bf16*  y1      = (bf16*)(ws + 235429888);    // end 268.98 MB

  prep_k<<<816, 256, 0, stream>>>(hidden, dones, W_emb, Wi, Wh, Wa1, Wa2, Wc1, Wc2,
                                  wembT, wiT, whT, wa1T, wa2T, wc1T, wc2T, h_state);
  for (int cs = -1; cs <= NCHUNK; ++cs) {
    fused_k<<<256, 256, 0, stream>>>(obs, b_emb, bi, wembT, wiT, xi0, xi1,
                                     dones, bh_n, whT, h_state, y0, y1, out_hidden,
                                     ba1, ba2, bc1, bc2, wa1T, wa2T, wc1T, wc2T,
                                     out_logits, out_v, cs);
  }
  (void)in_sizes; (void)n_in; (void)out_size; (void)ws_size;
}